// Round 1
// baseline (301.022 us; speedup 1.0000x reference)
//
#include <hip/hip_runtime.h>
#include <math.h>

// Problem constants
#define BS    2048            // batch
#define NROW  4096            // B*V
#define EDIM  256
#define NH    4
#define FSZ   64

__device__ __constant__ float c_dummy; // (unused)

static __device__ __forceinline__ float inv_temp() { return 1.0f / 0.07f; }

// ---------------- label bitmask kernel ----------------
__global__ void lab_kernel(const float* __restrict__ labels, unsigned* __restrict__ bits) {
    int i = blockIdx.x * blockDim.x + threadIdx.x;
    if (i < BS) {
        unsigned b = 0;
#pragma unroll
        for (int d = 0; d < 10; ++d)
            b |= (labels[i * 10 + d] != 0.0f ? 1u : 0u) << d;
        bits[i] = b;
    }
}

// ---------------- normalize kernel ----------------
// one block per row i of f (N rows); f[i] = features[i % B, i / B, :]
// wave w (threads 64w..64w+63) = head w's 64 elements
__global__ void norm_kernel(const float* __restrict__ feat, float* __restrict__ fn) {
    int i = blockIdx.x;
    int t = threadIdx.x;
    int b = i & (BS - 1);
    int v = i >> 11;
    float x = feat[(size_t)b * (2 * EDIM) + (size_t)v * EDIM + t];
    float ss = x * x;
#pragma unroll
    for (int off = 32; off > 0; off >>= 1)
        ss += __shfl_xor(ss, off, 64);
    float nrm = fmaxf(sqrtf(ss), 1e-12f);
    fn[(size_t)i * EDIM + t] = x / nrm;
}

// ---------------- main kernel ----------------
// grid (64 i-tiles, 8 j-chunks), block 256.
// Each block: rows [i0, i0+64), j in [jc0, jc0+512) as 8 tiles of 64.
// Thread (ti,tj) = (tid/16, tid%16) owns 4x4 (i x j) microtile across 4 heads.
// Accumulates per-row partials: S[h] (masked-out self), num = sum masked dotT[best],
// cnt[h] = masked count with argmax head h.  Shift M = 1/0.07 (cancels analytically).
__global__ __launch_bounds__(256) void main_kernel(
    const float* __restrict__ fn, const unsigned* __restrict__ bits,
    float* __restrict__ S, float* __restrict__ Num, float* __restrict__ Cnt) {

    __shared__ float shA[64][68];
    __shared__ float shB[64][68];
    __shared__ unsigned jb[64];
    __shared__ float sS[64][4];
    __shared__ float sN[64];
    __shared__ float sC[64][4];

    const int tid = threadIdx.x;
    const int ti = tid >> 4, tj = tid & 15;
    const int i0 = blockIdx.x * 64;
    const int jc0 = blockIdx.y * 512;
    const float INVT = inv_temp();
    const float MSH = INVT;

    if (tid < 64) {
        sN[tid] = 0.f;
#pragma unroll
        for (int h = 0; h < 4; ++h) { sS[tid][h] = 0.f; sC[tid][h] = 0.f; }
    }

    unsigned ib[4];
#pragma unroll
    for (int ii = 0; ii < 4; ++ii) ib[ii] = bits[(i0 + ti * 4 + ii) & (BS - 1)];

    float Sp[4][4] = {};  // [ii][h]
    float np[4] = {};
    float cp[4][4] = {};  // [ii][h]

    const int lr = tid >> 2;        // 0..63 staging row
    const int lc = (tid & 3) * 16;  // 0,16,32,48 staging col base

    for (int t = 0; t < 8; ++t) {
        const int j0 = jc0 + t * 64;
        float d[4][4][4] = {};  // [h][ii][jj]

#pragma unroll
        for (int h = 0; h < 4; ++h) {
            __syncthreads();
            {
                const float* sa = fn + (size_t)(i0 + lr) * EDIM + h * 64 + lc;
                const float* sb = fn + (size_t)(j0 + lr) * EDIM + h * 64 + lc;
#pragma unroll
                for (int q = 0; q < 4; ++q) {
                    *(float4*)&shA[lr][lc + q * 4] = *(const float4*)(sa + q * 4);
                    *(float4*)&shB[lr][lc + q * 4] = *(const float4*)(sb + q * 4);
                }
                if (h == 0 && tid < 64) jb[tid] = bits[(j0 + tid) & (BS - 1)];
            }
            __syncthreads();

#pragma unroll 2
            for (int kq = 0; kq < 16; ++kq) {
                float4 av[4], bv[4];
#pragma unroll
                for (int ii = 0; ii < 4; ++ii) av[ii] = *(const float4*)&shA[ti * 4 + ii][kq * 4];
#pragma unroll
                for (int jj = 0; jj < 4; ++jj) bv[jj] = *(const float4*)&shB[tj * 4 + jj][kq * 4];
#pragma unroll
                for (int ii = 0; ii < 4; ++ii)
#pragma unroll
                    for (int jj = 0; jj < 4; ++jj) {
                        float acc = d[h][ii][jj];
                        acc = fmaf(av[ii].x, bv[jj].x, acc);
                        acc = fmaf(av[ii].y, bv[jj].y, acc);
                        acc = fmaf(av[ii].z, bv[jj].z, acc);
                        acc = fmaf(av[ii].w, bv[jj].w, acc);
                        d[h][ii][jj] = acc;
                    }
            }
        }

        // postprocess the 16 pairs of this tile
#pragma unroll
        for (int ii = 0; ii < 4; ++ii) {
            const int i = i0 + ti * 4 + ii;
#pragma unroll
            for (int jj = 0; jj < 4; ++jj) {
                const int j = j0 + tj * 4 + jj;
                float dt0 = d[0][ii][jj] * INVT;
                float dt1 = d[1][ii][jj] * INVT;
                float dt2 = d[2][ii][jj] * INVT;
                float dt3 = d[3][ii][jj] * INVT;
                // argmax, first index wins ties (strict >)
                float bd = dt0; int bh = 0;
                if (dt1 > bd) { bd = dt1; bh = 1; }
                if (dt2 > bd) { bd = dt2; bh = 2; }
                if (dt3 > bd) { bd = dt3; bh = 3; }
                if (i != j) {
                    Sp[ii][0] += __expf(dt0 - MSH);
                    Sp[ii][1] += __expf(dt1 - MSH);
                    Sp[ii][2] += __expf(dt2 - MSH);
                    Sp[ii][3] += __expf(dt3 - MSH);
                    if (ib[ii] & jb[tj * 4 + jj]) {
                        np[ii] += bd;
#pragma unroll
                        for (int h = 0; h < 4; ++h)
                            cp[ii][h] += (bh == h) ? 1.0f : 0.0f;
                    }
                }
            }
        }
    }

    // combine thread partials within block via LDS atomics
#pragma unroll
    for (int ii = 0; ii < 4; ++ii) {
        int r = ti * 4 + ii;
        atomicAdd(&sN[r], np[ii]);
#pragma unroll
        for (int h = 0; h < 4; ++h) {
            atomicAdd(&sS[r][h], Sp[ii][h]);
            atomicAdd(&sC[r][h], cp[ii][h]);
        }
    }
    __syncthreads();
    if (tid < 64) {
        int i = i0 + tid;
        atomicAdd(&Num[i], sN[tid]);
#pragma unroll
        for (int h = 0; h < 4; ++h) {
            atomicAdd(&S[i * 4 + h], sS[tid][h]);
            atomicAdd(&Cnt[i * 4 + h], sC[tid][h]);
        }
    }
}

// ---------------- final reduction kernel ----------------
__global__ void final_kernel(const float* __restrict__ S, const float* __restrict__ Num,
                             const float* __restrict__ Cnt, float* __restrict__ out) {
    const float MSH = inv_temp();
    int tid = threadIdx.x;
    float ls = 0.f, lc = 0.f;
    for (int i = tid; i < NROW; i += 256) {
        float c = 0.f;
        float numr = Num[i];
#pragma unroll
        for (int h = 0; h < 4; ++h) {
            float sh = S[i * 4 + h];
            float ch = Cnt[i * 4 + h];
            numr -= ch * (MSH + logf(sh));
            c += ch;
        }
        if (c > 0.f) { ls += -(numr / c); lc += 1.f; }
    }
    __shared__ float rs[256], rc[256];
    rs[tid] = ls; rc[tid] = lc;
    __syncthreads();
    for (int s = 128; s > 0; s >>= 1) {
        if (tid < s) { rs[tid] += rs[tid + s]; rc[tid] += rc[tid + s]; }
        __syncthreads();
    }
    if (tid == 0) out[0] = rs[0] / rc[0];
}

extern "C" void kernel_launch(void* const* d_in, const int* in_sizes, int n_in,
                              void* d_out, int out_size, void* d_ws, size_t ws_size,
                              hipStream_t stream) {
    const float* feat = (const float*)d_in[0];    // (2048, 2, 256) f32
    const float* labels = (const float*)d_in[1];  // (2048, 10) f32
    float* out = (float*)d_out;

    char* ws = (char*)d_ws;
    float* fn = (float*)ws;                                   // N*E floats (4 MB)
    float* S = (float*)(ws + (size_t)NROW * EDIM * sizeof(float));  // N*4
    float* Num = S + NROW * 4;                                // N
    float* Cnt = Num + NROW;                                  // N*4
    unsigned* bits = (unsigned*)(Cnt + NROW * 4);             // BS uints

    // zero the S/Num/Cnt accumulators (contiguous N*9 floats)
    hipMemsetAsync(S, 0, (size_t)NROW * 9 * sizeof(float), stream);

    lab_kernel<<<8, 256, 0, stream>>>(labels, bits);
    norm_kernel<<<NROW, 256, 0, stream>>>(feat, fn);
    main_kernel<<<dim3(64, 8), 256, 0, stream>>>(fn, bits, S, Num, Cnt);
    final_kernel<<<1, 256, 0, stream>>>(S, Num, Cnt, out);
}

// Round 2
// 126.458 us; speedup vs baseline: 2.3804x; 2.3804x over previous
//
#include <hip/hip_runtime.h>
#include <math.h>

// Problem constants
#define BS    2048            // batch
#define NROW  4096            // B*V = N
#define EDIM  256
#define LDSW  264             // bf16 elems per LDS row: 256 + 8 pad (bank spread)
#define INVT  (1.0f/0.07f)

typedef float  float4v __attribute__((ext_vector_type(4)));
typedef short  short8v __attribute__((ext_vector_type(8)));

static __device__ __forceinline__ unsigned short f2bf(float x) {
    // round-to-nearest-even f32 -> bf16 (inputs are finite)
    unsigned u = __builtin_bit_cast(unsigned, x);
    u += 0x7fffu + ((u >> 16) & 1u);
    return (unsigned short)(u >> 16);
}

// ---------------- label bitmask kernel ----------------
__global__ void lab_kernel(const float* __restrict__ labels, unsigned* __restrict__ bits) {
    int i = blockIdx.x * blockDim.x + threadIdx.x;
    if (i < BS) {
        unsigned b = 0;
#pragma unroll
        for (int d = 0; d < 10; ++d)
            b |= (labels[i * 10 + d] != 0.0f ? 1u : 0u) << d;
        bits[i] = b;
    }
}

// ---------------- normalize kernel ----------------
// one block per row i of f; f[i] = features[i % B, i / B, :]; wave w = head w
__global__ void norm_kernel(const float* __restrict__ feat, unsigned short* __restrict__ fnb) {
    int i = blockIdx.x;
    int t = threadIdx.x;
    int b = i & (BS - 1);
    int v = i >> 11;
    float x = feat[(size_t)b * (2 * EDIM) + (size_t)v * EDIM + t];
    float ss = x * x;
#pragma unroll
    for (int off = 32; off > 0; off >>= 1)
        ss += __shfl_xor(ss, off, 64);
    float nrm = fmaxf(sqrtf(ss), 1e-12f);
    fnb[(size_t)i * EDIM + t] = f2bf(x / nrm);
}

// ---------------- main kernel (bf16 MFMA core) ----------------
// grid (64 i-tiles, 8 j-chunks), block 256 = 4 waves.
// Block: rows [i0,i0+64), j in [jc0,jc0+512) as 8 tiles of 64.
// Wave w: i-subrange (w>>1)*32, j-subrange (w&1)*32 of the tile -> 2x2 16x16
// MFMA subtiles x 4 heads.  A fragments (invariant over j) hoisted to regs,
// loaded directly from global (fn_bf = 2 MB, L2-resident).  B tile staged in
// LDS bf16 with +8 elem row pad.
// C/D layout (verified m89/m91): col = lane&15, row = (lane>>4)*4 + reg.
// A/B operand layout: lane l -> row/col = l&15, k = (l>>4)*8 + [0..8).
__global__ __launch_bounds__(256, 2) void main_kernel(
    const unsigned short* __restrict__ fnb, const unsigned* __restrict__ bits,
    float* __restrict__ S, float* __restrict__ Num, float* __restrict__ Cnt) {

    __shared__ unsigned short shB[64 * LDSW];

    const int tid  = threadIdx.x;
    const int lane = tid & 63;
    const int wave = tid >> 6;
    const int quad = lane >> 4;
    const int ml   = lane & 15;
    const int i0   = blockIdx.x * 64;
    const int jc0  = blockIdx.y * 512;
    const int wi   = (wave >> 1) * 32;
    const int wj   = (wave & 1) * 32;
    const float MSH = INVT;  // fixed shift; cancels analytically in log_prob

    // A fragments: af[isub][h][khalf], 16 x short8 = 64 VGPRs
    short8v af[2][4][2];
#pragma unroll
    for (int is = 0; is < 2; ++is) {
        const unsigned short* ap = fnb + (size_t)(i0 + wi + is * 16 + ml) * EDIM + quad * 8;
#pragma unroll
        for (int h = 0; h < 4; ++h)
#pragma unroll
            for (int kk = 0; kk < 2; ++kk)
                af[is][h][kk] = *(const short8v*)(ap + h * 64 + kk * 32);
    }

    // label bits for the 8 rows this lane owns (p = isub*4 + reg)
    unsigned ibr[8];
#pragma unroll
    for (int p = 0; p < 8; ++p)
        ibr[p] = bits[(i0 + wi + (p >> 2) * 16 + quad * 4 + (p & 3)) & (BS - 1)];

    // per-lane per-row partials over the whole j-chunk
    float Sp[8][4] = {};
    float np[8] = {};
    int   cpk[8] = {};   // 4 x 8-bit packed argmax-head counts (max 16/row/lane)

    for (int t = 0; t < 8; ++t) {
        const int j0 = jc0 + t * 64;
        __syncthreads();
#pragma unroll
        for (int q = 0; q < 8; ++q) {
            int s = tid + 256 * q;             // 0..2047 16B segments
            int r = s >> 5, c = (s & 31) * 8;  // row, col (bf16 elems)
            *(uint4*)(shB + r * LDSW + c) = *(const uint4*)(fnb + (size_t)(j0 + r) * EDIM + c);
        }
        __syncthreads();

        const unsigned jb0 = bits[(j0 + wj + ml) & (BS - 1)];
        const unsigned jb1 = bits[(j0 + wj + 16 + ml) & (BS - 1)];

        float4v dacc[2][2][4];
#pragma unroll
        for (int a = 0; a < 2; ++a)
#pragma unroll
            for (int b = 0; b < 2; ++b)
#pragma unroll
                for (int h = 0; h < 4; ++h)
                    dacc[a][b][h] = (float4v){0.f, 0.f, 0.f, 0.f};

#pragma unroll
        for (int h = 0; h < 4; ++h)
#pragma unroll
            for (int kk = 0; kk < 2; ++kk) {
                const int ko = h * 64 + kk * 32 + quad * 8;
                short8v b0 = *(const short8v*)(shB + (wj + ml) * LDSW + ko);
                short8v b1 = *(const short8v*)(shB + (wj + 16 + ml) * LDSW + ko);
                dacc[0][0][h] = __builtin_amdgcn_mfma_f32_16x16x32_bf16(af[0][h][kk], b0, dacc[0][0][h], 0, 0, 0);
                dacc[0][1][h] = __builtin_amdgcn_mfma_f32_16x16x32_bf16(af[0][h][kk], b1, dacc[0][1][h], 0, 0, 0);
                dacc[1][0][h] = __builtin_amdgcn_mfma_f32_16x16x32_bf16(af[1][h][kk], b0, dacc[1][0][h], 0, 0, 0);
                dacc[1][1][h] = __builtin_amdgcn_mfma_f32_16x16x32_bf16(af[1][h][kk], b1, dacc[1][1][h], 0, 0, 0);
            }

        // epilogue: 16 (i,j) pairs per lane, 4 heads each
#pragma unroll
        for (int is = 0; is < 2; ++is)
#pragma unroll
            for (int r = 0; r < 4; ++r) {
                const int p = is * 4 + r;
                const int i = i0 + wi + is * 16 + quad * 4 + r;
                const unsigned ibit = ibr[p];
#pragma unroll
                for (int js = 0; js < 2; ++js) {
                    const int j = j0 + wj + js * 16 + ml;
                    const unsigned jbit = js ? jb1 : jb0;
                    const float d0 = dacc[is][js][0][r];
                    const float d1 = dacc[is][js][1][r];
                    const float d2 = dacc[is][js][2][r];
                    const float d3 = dacc[is][js][3][r];
                    // argmax, first index wins ties
                    float bd = d0; int bh = 0;
                    if (d1 > bd) { bd = d1; bh = 1; }
                    if (d2 > bd) { bd = d2; bh = 2; }
                    if (d3 > bd) { bd = d3; bh = 3; }
                    const bool off = (i != j);
                    const float e0 = __expf(fmaf(d0, INVT, -MSH));
                    const float e1 = __expf(fmaf(d1, INVT, -MSH));
                    const float e2 = __expf(fmaf(d2, INVT, -MSH));
                    const float e3 = __expf(fmaf(d3, INVT, -MSH));
                    if (off) {
                        Sp[p][0] += e0; Sp[p][1] += e1; Sp[p][2] += e2; Sp[p][3] += e3;
                    }
                    if (off && (ibit & jbit)) {
                        np[p] += bd;            // raw dot; * INVT at flush
                        cpk[p] += 1 << (bh * 8);
                    }
                }
            }
    }

    // reduce the 16 lanes sharing each row, then one global atomic per value
#pragma unroll
    for (int p = 0; p < 8; ++p) {
        const int i = i0 + wi + (p >> 2) * 16 + quad * 4 + (p & 3);
        float v[9];
        v[0] = np[p];
#pragma unroll
        for (int h = 0; h < 4; ++h) v[1 + h] = Sp[p][h];
#pragma unroll
        for (int h = 0; h < 4; ++h) v[5 + h] = (float)((cpk[p] >> (8 * h)) & 255);
#pragma unroll
        for (int k = 0; k < 9; ++k) {
            float x = v[k];
            x += __shfl_xor(x, 1, 64);
            x += __shfl_xor(x, 2, 64);
            x += __shfl_xor(x, 4, 64);
            x += __shfl_xor(x, 8, 64);
            v[k] = x;
        }
        if (ml == 0) {
            atomicAdd(&Num[i], v[0] * INVT);
#pragma unroll
            for (int h = 0; h < 4; ++h) atomicAdd(&S[i * 4 + h], v[1 + h]);
#pragma unroll
            for (int h = 0; h < 4; ++h) atomicAdd(&Cnt[i * 4 + h], v[5 + h]);
        }
    }
}

// ---------------- final reduction kernel ----------------
__global__ void final_kernel(const float* __restrict__ S, const float* __restrict__ Num,
                             const float* __restrict__ Cnt, float* __restrict__ out) {
    const float MSH = INVT;
    int tid = threadIdx.x;
    float ls = 0.f, lc = 0.f;
    for (int i = tid; i < NROW; i += 1024) {
        float c = 0.f;
        float numr = Num[i];
#pragma unroll
        for (int h = 0; h < 4; ++h) {
            float sh = S[i * 4 + h];
            float ch = Cnt[i * 4 + h];
            numr -= ch * (MSH + logf(sh));
            c += ch;
        }
        if (c > 0.f) { ls += -(numr / c); lc += 1.f; }
    }
    __shared__ float rs[1024], rc[1024];
    rs[tid] = ls; rc[tid] = lc;
    __syncthreads();
    for (int s = 512; s > 0; s >>= 1) {
        if (tid < s) { rs[tid] += rs[tid + s]; rc[tid] += rc[tid + s]; }
        __syncthreads();
    }
    if (tid == 0) out[0] = rs[0] / rc[0];
}

extern "C" void kernel_launch(void* const* d_in, const int* in_sizes, int n_in,
                              void* d_out, int out_size, void* d_ws, size_t ws_size,
                              hipStream_t stream) {
    const float* feat = (const float*)d_in[0];    // (2048, 2, 256) f32
    const float* labels = (const float*)d_in[1];  // (2048, 10) f32
    float* out = (float*)d_out;

    char* ws = (char*)d_ws;
    unsigned short* fnb = (unsigned short*)ws;                     // N*E bf16 (2 MB)
    float* S = (float*)(ws + (size_t)NROW * EDIM * sizeof(unsigned short));
    float* Num = S + NROW * 4;
    float* Cnt = Num + NROW;
    unsigned* bits = (unsigned*)(Cnt + NROW * 4);

    hipMemsetAsync(S, 0, (size_t)NROW * 9 * sizeof(float), stream);

    lab_kernel<<<8, 256, 0, stream>>>(labels, bits);
    norm_kernel<<<NROW, 256, 0, stream>>>(feat, fnb);
    main_kernel<<<dim3(64, 8), 256, 0, stream>>>(fnb, bits, S, Num, Cnt);
    final_kernel<<<1, 1024, 0, stream>>>(S, Num, Cnt, out);
}

// Round 3
// 116.620 us; speedup vs baseline: 2.5812x; 1.0844x over previous
//
#include <hip/hip_runtime.h>
#include <math.h>

// Problem constants
#define BS    2048            // batch
#define NROW  4096            // B*V = N
#define EDIM  256
#define INVT  (1.0f/0.07f)

typedef float  float4v __attribute__((ext_vector_type(4)));
typedef short  short8v __attribute__((ext_vector_type(8)));

static __device__ __forceinline__ unsigned short f2bf(float x) {
    // round-to-nearest-even f32 -> bf16 (inputs are finite)
    unsigned u = __builtin_bit_cast(unsigned, x);
    u += 0x7fffu + ((u >> 16) & 1u);
    return (unsigned short)(u >> 16);
}

static __device__ __forceinline__ void gload_lds16(const void* g, void* l) {
    __builtin_amdgcn_global_load_lds(
        (const __attribute__((address_space(1))) unsigned int*)g,
        (__attribute__((address_space(3))) unsigned int*)l, 16, 0, 0);
}

// ---------------- prep kernel: normalize + label bits + zero accumulators ----
// blocks 0..4095: row normalize (wave w = head w); blocks 4096..4103: labels + zeroing
__global__ void prep_kernel(const float* __restrict__ feat, const float* __restrict__ labels,
                            unsigned short* __restrict__ fnb, unsigned* __restrict__ bits,
                            float* __restrict__ zacc) {
    const int b = blockIdx.x, t = threadIdx.x;
    if (b < NROW) {
        int bb = b & (BS - 1);
        int v = b >> 11;
        float x = feat[(size_t)bb * (2 * EDIM) + (size_t)v * EDIM + t];
        float ss = x * x;
#pragma unroll
        for (int off = 32; off > 0; off >>= 1)
            ss += __shfl_xor(ss, off, 64);
        float nrm = fmaxf(sqrtf(ss), 1e-12f);
        fnb[(size_t)b * EDIM + t] = f2bf(x / nrm);
    } else {
        int g = (b - NROW) * 256 + t;   // 0..2047
        unsigned bb = 0;
#pragma unroll
        for (int d = 0; d < 10; ++d)
            bb |= (labels[g * 10 + d] != 0.0f ? 1u : 0u) << d;
        bits[g] = bb;
        // zero S (N*4), Num (N), Cnt (N*4), red[2], done[1] = N*9+3 words
        for (int k = g; k < NROW * 9 + 3; k += 2048) zacc[k] = 0.0f;
    }
}

// ---------------- main kernel (bf16 MFMA core, async LDS staging) ----------
// grid (64 i-tiles, 16 j-chunks), block 256 = 4 waves.
// Block: rows [bx*64, bx*64+64), j in [by*256, by*256+256) as 4 tiles of 64.
// Wave w: i-rows [bx*64 + w*16, +16) x all 64 j of the tile -> 1x4 16x16 MFMA
// subtiles x 4 heads.  A fragments hoisted to regs from global (L2-resident).
// B tile staged in LDS bf16 via global_load_lds (16B), XOR-granule swizzle
// g_lds = g ^ (row&7) -> staging dest is linear (uniform + lane*16) AND
// fragment ds_read_b128 is conflict-free (2-way only, free per m136).
// C/D layout (m89/m91): col = lane&15, row = (lane>>4)*4 + reg.
// A/B operand layout: lane l -> m/n = l&15, k = (l>>4)*8 + [0..8).
__global__ __launch_bounds__(256, 3) void main_kernel(
    const unsigned short* __restrict__ fnb, const unsigned* __restrict__ bits,
    float* __restrict__ S, float* __restrict__ Num, float* __restrict__ Cnt) {

    __shared__ unsigned short shB[64 * 256];   // 32 KiB, swizzled granules

    const int tid  = threadIdx.x;
    const int lane = tid & 63;
    const int wave = tid >> 6;
    const int quad = lane >> 4;
    const int ml   = lane & 15;
    const int xr   = ml & 7;                   // swizzle XOR for this lane's rows
    const int i0   = blockIdx.x * 64 + wave * 16;
    const int jc0  = blockIdx.y * 256;

    // A fragments: af[h][kk], 8 x short8 = 32 VGPRs (rows i0..i0+15)
    short8v af[4][2];
    {
        const unsigned short* ap = fnb + (size_t)(i0 + ml) * EDIM + quad * 8;
#pragma unroll
        for (int h = 0; h < 4; ++h)
#pragma unroll
            for (int kk = 0; kk < 2; ++kk)
                af[h][kk] = *(const short8v*)(ap + h * 64 + kk * 32);
    }

    unsigned ibr[4];
#pragma unroll
    for (int r = 0; r < 4; ++r)
        ibr[r] = bits[(i0 + quad * 4 + r) & (BS - 1)];

    float    Sp[4][4] = {};
    float    np[4] = {};
    unsigned cpk[4] = {};   // per row: 4 x 8-bit argmax-head counts (max 16)

    for (int t = 0; t < 4; ++t) {
        const int j0 = jc0 + t * 64;
        __syncthreads();   // prior tile's reads done before overwrite
#pragma unroll
        for (int q = 0; q < 8; ++q) {
            const int G   = tid + 256 * q;          // LDS 16B-granule index
            const int row = G >> 5;
            const int gg  = (G & 31) ^ (row & 7);   // global granule (swizzle)
            gload_lds16(fnb + (size_t)(j0 + row) * EDIM + gg * 8, shB + G * 8);
        }
        __syncthreads();   // drains vmcnt -> staged data visible

        unsigned jbr[4];
#pragma unroll
        for (int js = 0; js < 4; ++js)
            jbr[js] = bits[(j0 + js * 16 + ml) & (BS - 1)];

        float4v dacc[4][4];   // [js][h]
#pragma unroll
        for (int js = 0; js < 4; ++js)
#pragma unroll
            for (int h = 0; h < 4; ++h)
                dacc[js][h] = (float4v){0.f, 0.f, 0.f, 0.f};

#pragma unroll
        for (int h = 0; h < 4; ++h)
#pragma unroll
            for (int kk = 0; kk < 2; ++kk) {
                const int gsw = ((h * 8 + kk * 4 + quad) ^ xr) * 8;  // elem offset
#pragma unroll
                for (int js = 0; js < 4; ++js) {
                    short8v bf = *(const short8v*)(shB + (js * 16 + ml) * 256 + gsw);
                    dacc[js][h] = __builtin_amdgcn_mfma_f32_16x16x32_bf16(af[h][kk], bf, dacc[js][h], 0, 0, 0);
                }
            }

        // epilogue: 16 (i,j) pairs per lane, 4 heads each
#pragma unroll
        for (int r = 0; r < 4; ++r) {
            const int i = i0 + quad * 4 + r;
            const unsigned ibit = ibr[r];
#pragma unroll
            for (int js = 0; js < 4; ++js) {
                const int j = j0 + js * 16 + ml;
                const float d0 = dacc[js][0][r];
                const float d1 = dacc[js][1][r];
                const float d2 = dacc[js][2][r];
                const float d3 = dacc[js][3][r];
                // argmax, first index wins ties
                float bd = d0; int bh = 0;
                if (d1 > bd) { bd = d1; bh = 1; }
                if (d2 > bd) { bd = d2; bh = 2; }
                if (d3 > bd) { bd = d3; bh = 3; }
                const bool off = (i != j);
                const float e0 = __expf(fmaf(d0, INVT, -INVT));
                const float e1 = __expf(fmaf(d1, INVT, -INVT));
                const float e2 = __expf(fmaf(d2, INVT, -INVT));
                const float e3 = __expf(fmaf(d3, INVT, -INVT));
                if (off) {
                    Sp[r][0] += e0; Sp[r][1] += e1; Sp[r][2] += e2; Sp[r][3] += e3;
                }
                if (off && (ibit & jbr[js])) {
                    np[r] += bd;              // raw dot; * INVT at flush
                    cpk[r] += 1u << (bh * 8);
                }
            }
        }
    }

    // reduce the 16 lanes sharing each row, then one global atomic per value
#pragma unroll
    for (int r = 0; r < 4; ++r) {
        const int i = i0 + quad * 4 + r;
        float v[9];
        v[0] = np[r];
#pragma unroll
        for (int h = 0; h < 4; ++h) v[1 + h] = Sp[r][h];
#pragma unroll
        for (int h = 0; h < 4; ++h) v[5 + h] = (float)((cpk[r] >> (8 * h)) & 255u);
#pragma unroll
        for (int k = 0; k < 9; ++k) {
            float x = v[k];
            x += __shfl_xor(x, 1, 64);
            x += __shfl_xor(x, 2, 64);
            x += __shfl_xor(x, 4, 64);
            x += __shfl_xor(x, 8, 64);
            v[k] = x;
        }
        if (ml == 0) {
            atomicAdd(&Num[i], v[0] * INVT);
#pragma unroll
            for (int h = 0; h < 4; ++h) atomicAdd(&S[i * 4 + h], v[1 + h]);
#pragma unroll
            for (int h = 0; h < 4; ++h) atomicAdd(&Cnt[i * 4 + h], v[5 + h]);
        }
    }
}

// ---------------- final reduction: 16 blocks, last block writes out --------
__global__ void final_kernel(const float* __restrict__ S, const float* __restrict__ Num,
                             const float* __restrict__ Cnt, float* __restrict__ red,
                             unsigned* __restrict__ done, float* __restrict__ out) {
    const int tid = threadIdx.x;
    const int i = blockIdx.x * 256 + tid;   // grid 16 x 256 = 4096 rows exactly
    float c = 0.f;
    float numr = Num[i];
#pragma unroll
    for (int h = 0; h < 4; ++h) {
        float sh = S[i * 4 + h];
        float ch = Cnt[i * 4 + h];
        numr -= ch * (INVT + logf(sh));
        c += ch;
    }
    float ls = 0.f, lc = 0.f;
    if (c > 0.f) { ls = -(numr / c); lc = 1.f; }

    __shared__ float rs[256], rc[256];
    rs[tid] = ls; rc[tid] = lc;
    __syncthreads();
    for (int s = 128; s > 0; s >>= 1) {
        if (tid < s) { rs[tid] += rs[tid + s]; rc[tid] += rc[tid + s]; }
        __syncthreads();
    }
    if (tid == 0) {
        atomicAdd(&red[0], rs[0]);
        atomicAdd(&red[1], rc[0]);
        __threadfence();
        if (atomicAdd(done, 1u) == 15u) {
            float s = atomicAdd(&red[0], 0.0f);
            float cc = atomicAdd(&red[1], 0.0f);
            out[0] = s / cc;
        }
    }
}

extern "C" void kernel_launch(void* const* d_in, const int* in_sizes, int n_in,
                              void* d_out, int out_size, void* d_ws, size_t ws_size,
                              hipStream_t stream) {
    const float* feat = (const float*)d_in[0];    // (2048, 2, 256) f32
    const float* labels = (const float*)d_in[1];  // (2048, 10) f32
    float* out = (float*)d_out;

    char* ws = (char*)d_ws;
    unsigned short* fnb = (unsigned short*)ws;                     // N*E bf16 (2 MB)
    float* S = (float*)(ws + (size_t)NROW * EDIM * sizeof(unsigned short));
    float* Num = S + NROW * 4;
    float* Cnt = Num + NROW;
    float* red = Cnt + NROW * 4;              // red[0]=sum, red[1]=count
    unsigned* done = (unsigned*)(red + 2);    // completion counter
    unsigned* bits = done + 1;                // BS label bitmasks

    prep_kernel<<<NROW + 8, 256, 0, stream>>>(feat, labels, fnb, bits, S);
    main_kernel<<<dim3(64, 16), 256, 0, stream>>>(fnb, bits, S, Num, Cnt);
    final_kernel<<<16, 256, 0, stream>>>(S, Num, Cnt, red, done, out);
}